// Round 6
// baseline (361.955 us; speedup 1.0000x reference)
//
#include <hip/hip_runtime.h>
#include <hip/hip_bf16.h>

#define N_NODES 100000
#define C_DIM   160
#define R_REL   10
#define B_BLK   5
#define CB      32
#define E_EDGES 500000
#define M_SEG   (N_NODES*R_REL)   // 1,000,000 (dst,rel) segments
#define NB      16                // nodes per block (1 per wave, 16 waves)
#define ASTRIDE 1768              // ushorts per node row in LDS (221*16B: odd 16B stride)
#define NCHUNK  ((M_SEG + 4095)/4096)   // 245

#define CVT_TOTAL  (N_NODES*C_DIM/8)          // 2,000,000 uint4-of-bf16 per thread
#define CVT_BLKS   ((CVT_TOTAL + 255)/256)    // 7813
#define ZERO_TOTAL (M_SEG/4)                  // 250,000 int4 stores
#define ZERO_BLKS  ((ZERO_TOTAL + 255)/256)   // 977
#define WPK_BLKS   ((2*10*15*64 + 255)/256)   // 75

typedef float f32x4 __attribute__((ext_vector_type(4)));
typedef short s16x8 __attribute__((ext_vector_type(8)));

__device__ __forceinline__ float b2f(unsigned short h){ return __uint_as_float(((unsigned)h)<<16); }
__device__ __forceinline__ unsigned pack2(float a, float b){
  union { __hip_bfloat162 h; unsigned u; } cv;
  cv.h = __float22bfloat162_rn(make_float2(a, b));   // v_cvt_pk_bf16_f32 (RNE)
  return cv.u;
}
__device__ __forceinline__ unsigned short f2b(float f){
  unsigned b = __float_as_uint(f);
  b += 0x7FFFu + ((b>>16)&1u);
  return (unsigned short)(b>>16);
}
__device__ __forceinline__ float4 unpack4(uint2 u){
  return make_float4(b2f((unsigned short)(u.x & 0xFFFF)), b2f((unsigned short)(u.x >> 16)),
                     b2f((unsigned short)(u.y & 0xFFFF)), b2f((unsigned short)(u.y >> 16)));
}

// ---------------- fused prep: fp32->bf16 cvt  |  deg zero  |  weight repack ----------------
// wpack layout: wp[((ct*15+ko)*64+lane)*8 + j] = B[k][col], col = ct*16+(lane&15),
// k = ko*32+(lane>>4)*8+j ; k<320: w[r=ko][b=col/32][k%32][col%32] ; k>=320: root[k-320][col]
__global__ __launch_bounds__(256) void k_prep(const float* __restrict__ ne, unsigned short* __restrict__ x0b,
                                              int* __restrict__ deg,
                                              const float* __restrict__ w1, const float* __restrict__ root1,
                                              unsigned short* __restrict__ wp1,
                                              const float* __restrict__ w2, const float* __restrict__ root2,
                                              unsigned short* __restrict__ wp2){
  const int b = blockIdx.x;
  const int t = threadIdx.x;
  if (b < CVT_BLKS){
    if (x0b){
      const int i = b*256 + t;
      if (i < CVT_TOTAL){
        const float4* p = (const float4*)ne + (size_t)i*2;
        float4 a = p[0], c = p[1];
        uint4 w;
        w.x = pack2(a.x, a.y); w.y = pack2(a.z, a.w);
        w.z = pack2(c.x, c.y); w.w = pack2(c.z, c.w);
        ((uint4*)x0b)[i] = w;
      }
    }
    return;
  }
  if (b < CVT_BLKS + ZERO_BLKS){
    const int i = (b - CVT_BLKS)*256 + t;
    if (i < ZERO_TOTAL) ((int4*)deg)[i] = make_int4(0,0,0,0);
    return;
  }
  {
    const int tid0 = (b - CVT_BLKS - ZERO_BLKS)*256 + t;
    if (tid0 >= 2*10*15*64) return;
    const int which = (tid0 >= 9600);
    const int tid = which ? tid0 - 9600 : tid0;
    const float* w    = which ? w2 : w1;
    const float* root = which ? root2 : root1;
    unsigned short* wp = which ? wp2 : wp1;
    const int l  = tid & 63;
    const int ko = (tid>>6) % 15;
    const int ct = tid / (15*64);
    const int col16 = l & 15, kq = l >> 4;
    const int cout = ct*16 + col16;
    const int bb = cout >> 5, d = cout & 31;
    unsigned short* dstp = wp + (size_t)tid*8;
    #pragma unroll
    for (int j=0;j<8;++j){
      float f;
      if (ko < 10){
        int cl = kq*8 + j;
        f = w[((ko*B_BLK + bb)*CB + cl)*CB + d];
      } else {
        int ci = (ko-10)*32 + kq*8 + j;
        f = root[ci*C_DIM + cout];
      }
      dstp[j] = f2b(f);
    }
  }
}

// ---------------- CSR build over (dst,rel) segments ----------------
__global__ __launch_bounds__(256) void k_count(const int* __restrict__ dst, const int* __restrict__ et,
                                               int* __restrict__ deg){
  int e = blockIdx.x*256 + threadIdx.x;
  if (e < E_EDGES) atomicAdd(&deg[dst[e]*R_REL + et[e]], 1);
}

__global__ __launch_bounds__(256) void k_scan1(const int* __restrict__ deg, int* __restrict__ rowptr,
                                               int* __restrict__ sums){
  __shared__ int lds[256];
  const int t = threadIdx.x;
  const int base = blockIdx.x*4096 + t*16;
  int v[16]; int tot = 0;
  #pragma unroll
  for (int i=0;i<16;++i){
    int idx = base+i;
    int d = (idx < M_SEG) ? deg[idx] : 0;
    v[i] = tot; tot += d;
  }
  lds[t] = tot;
  __syncthreads();
  for (int off=1; off<256; off<<=1){
    int x = (t>=off) ? lds[t-off] : 0;
    __syncthreads();
    lds[t] += x;
    __syncthreads();
  }
  const int excl = lds[t] - tot;
  #pragma unroll
  for (int i=0;i<16;++i){
    int idx = base+i;
    if (idx < M_SEG) rowptr[idx] = excl + v[i];
  }
  if (t == 0) sums[blockIdx.x] = lds[255];
}

// fused scan2+scan3: each block re-scans the NCHUNK partials, applies its chunk prefix.
// Block covers 1024 segments -> chunk = blockIdx>>2 (uniform within block).
__global__ __launch_bounds__(256) void k_scan23(int* __restrict__ rowptr, int* __restrict__ cursor,
                                                const int* __restrict__ sums){
  __shared__ int lds[256];
  const int t = threadIdx.x;
  lds[t] = (t < NCHUNK) ? sums[t] : 0;
  __syncthreads();
  for (int off=1; off<256; off<<=1){
    int x = (t>=off) ? lds[t-off] : 0;
    __syncthreads();
    lds[t] += x;
    __syncthreads();
  }
  const int chunk = blockIdx.x >> 2;
  const int pre = (chunk == 0) ? 0 : lds[chunk-1];
  #pragma unroll
  for (int k=0;k<4;++k){
    int i = blockIdx.x*1024 + k*256 + t;
    if (i < M_SEG){
      int val = rowptr[i] + pre;
      rowptr[i] = val;
      cursor[i] = val;
    }
  }
  if (blockIdx.x == 0 && t == 0) rowptr[M_SEG] = lds[NCHUNK-1];
}

// scatter packed (src | rel<<20) into (dst,rel)-sorted order
__global__ __launch_bounds__(256) void k_scatter(const int* __restrict__ src, const int* __restrict__ dst,
                                                 const int* __restrict__ et, int* __restrict__ cursor,
                                                 unsigned* __restrict__ pked){
  int e = blockIdx.x*256 + threadIdx.x;
  if (e < E_EDGES){
    int r = et[e];
    int seg = dst[e]*R_REL + r;
    int pos = atomicAdd(&cursor[seg], 1);
    pked[pos] = (unsigned)src[e] | ((unsigned)r << 20);
  }
}

// ---------------- fused layer ----------------
// 1024 threads = 16 waves; wave w aggregates node nb+w.
// Phase A: batch-load packed edges; per 8-group: readlane all, issue all 8 gathers,
// then uniform flush-on-rel-change accumulate (CSR is (dst,rel)-sorted).
// Phase B: waves 0..9 one 16-col tile each, K=480 (15 MFMA).
template<int XF32, int RELU>
__global__ __launch_bounds__(1024, 8) void k_layer(
    const float* __restrict__ xf,            // fp32 features (fallback path)
    const unsigned short* __restrict__ xb,   // bf16 features
    const int* __restrict__ rowptr,          // (dst,rel) rowptr, M_SEG+1
    const unsigned* __restrict__ pked,       // packed src|rel<<20
    const unsigned short* __restrict__ wpack,
    const float* __restrict__ bias,
    float* __restrict__ outf,
    unsigned short* __restrict__ outb)
{
  __shared__ unsigned short A[NB*ASTRIDE];
  const int tid  = threadIdx.x;
  const int wave = __builtin_amdgcn_readfirstlane(tid >> 6);
  const int lane = tid & 63;
  const int nb   = blockIdx.x * NB;
  const int n    = nb + wave;
  const int m    = wave;
  const int lc   = (lane < 40) ? lane : (lane - 40);   // channel-quad index
  const bool act = (lane < 40);
  constexpr int GD = XF32 ? 4 : 8;                     // gather depth

  // pre-zero the 10 mean rows (covers empty segments)
  if (act){
    #pragma unroll
    for (int r=0;r<R_REL;++r)
      *(uint2*)&A[m*ASTRIDE + r*C_DIM + 4*lane] = make_uint2(0u,0u);
  }

  const int e0 = rowptr[n*R_REL];
  const int e1 = rowptr[n*R_REL + R_REL];

  int r_cur = -1, ecnt = 0;
  float4 acc = make_float4(0.f,0.f,0.f,0.f);

  for (int eb = e0; eb < e1; eb += 64){
    const int cnt = min(64, e1 - eb);
    unsigned pkl = (eb + lane < e1) ? pked[eb + lane] : 0u;
    for (int j = 0; j < cnt; j += GD){
      const int g = min(GD, cnt - j);
      unsigned pk[GD];
      #pragma unroll
      for (int u=0; u<GD; ++u){
        const int idx = (j+u < cnt) ? (j+u) : (cnt-1);   // clamp: dup gathers, masked below
        pk[u] = (unsigned)__builtin_amdgcn_readlane((int)pkl, idx);
      }
      uint2  gb[GD];
      float4 gf[GD];
      #pragma unroll
      for (int u=0; u<GD; ++u){
        if (XF32) gf[u] = ((const float4*)(xf + (size_t)(pk[u] & 0xFFFFFu)*C_DIM))[lc];
        else      gb[u] = ((const uint2*)(xb + (size_t)(pk[u] & 0xFFFFFu)*C_DIM))[lc];
      }
      #pragma unroll
      for (int u=0; u<GD; ++u){
        if (u < g){                                      // uniform predicate
          const int rl = (int)(pk[u] >> 20);
          if (rl != r_cur){
            if (r_cur >= 0){
              const float s = __builtin_amdgcn_rcpf((float)ecnt);
              if (act){
                uint2 wv; wv.x = pack2(acc.x*s, acc.y*s); wv.y = pack2(acc.z*s, acc.w*s);
                *(uint2*)&A[m*ASTRIDE + r_cur*C_DIM + 4*lane] = wv;
              }
            }
            r_cur = rl; ecnt = 0; acc = make_float4(0.f,0.f,0.f,0.f);
          }
          float4 gv = XF32 ? gf[u] : unpack4(gb[u]);
          acc.x += gv.x; acc.y += gv.y; acc.z += gv.z; acc.w += gv.w; ecnt++;
        }
      }
    }
  }
  if (r_cur >= 0){
    const float s = __builtin_amdgcn_rcpf((float)ecnt);
    if (act){
      uint2 wv; wv.x = pack2(acc.x*s, acc.y*s); wv.y = pack2(acc.z*s, acc.w*s);
      *(uint2*)&A[m*ASTRIDE + r_cur*C_DIM + 4*lane] = wv;
    }
  }
  { // root row: x[n] at K-offset 1600
    if (XF32){
      float4 v = ((const float4*)(xf + (size_t)n*C_DIM))[lc];
      if (act){
        uint2 wv; wv.x = pack2(v.x, v.y); wv.y = pack2(v.z, v.w);
        *(uint2*)&A[m*ASTRIDE + 1600 + 4*lane] = wv;
      }
    } else {
      uint2 rw = ((const uint2*)(xb + (size_t)n*C_DIM))[lc];
      if (act) *(uint2*)&A[m*ASTRIDE + 1600 + 4*lane] = rw;
    }
  }
  __syncthreads();

  // ---- Phase B: waves 0..9 -> col-tile ct = wave ; K = 480 (15 MFMA steps)
  if (wave < 10){
    const int ct = wave;
    const int b = ct >> 1;
    const int row16 = lane & 15;   // A row (node) / D col
    const int kq    = lane >> 4;   // k-chunk
    f32x4 c = {0.f, 0.f, 0.f, 0.f};
    #pragma unroll
    for (int ko=0; ko<15; ++ko){
      const int aoff = row16*ASTRIDE + (ko < 10 ? ko*C_DIM + b*CB + kq*8
                                                : 1600 + (ko-10)*CB + kq*8);
      s16x8 af  = *(const s16x8*)&A[aoff];
      s16x8 bfv = *(const s16x8*)&wpack[(size_t)((ct*15+ko)*64 + lane)*8];
      c = __builtin_amdgcn_mfma_f32_16x16x32_bf16(af, bfv, c, 0, 0, 0);
    }
    const int col = ct*16 + row16;
    const float bv = bias[col];
    #pragma unroll
    for (int q=0;q<4;++q){
      const int nn = nb + kq*4 + q;          // D row = (lane>>4)*4 + q
      float v = c[q] + bv;
      if (RELU) v = fmaxf(v, 0.f);
      if (outf) outf[(size_t)nn*C_DIM + col] = v;
      if (outb) outb[(size_t)nn*C_DIM + col] = f2b(v);
    }
  }
}

// ---------------- ws layout (bytes) ----------------
static constexpr size_t X1_OFF  = 0;                          // bf16 x1: 32,000,000
static constexpr size_t RP_OFF  = 32000000;                   // rowptr (M_SEG+1)*4
static constexpr size_t DC_OFF  = RP_OFF + 4000016;           // deg/cursor (aliased) M_SEG*4
static constexpr size_t PK_OFF  = DC_OFF + 4000000;           // packed edges E*4
static constexpr size_t SUM_OFF = PK_OFF + 2000000;           // scan sums
static constexpr size_t WP1_OFF = SUM_OFF + 1024;             // 153,600
static constexpr size_t WP2_OFF = WP1_OFF + 153600;           // 153,600
static constexpr size_t X0B_OFF = WP2_OFF + 153600;           // bf16 node_emb: 32,000,000
static constexpr size_t WS_NEED = X0B_OFF + 32000000;         // ~74.3 MB

extern "C" void kernel_launch(void* const* d_in, const int* in_sizes, int n_in,
                              void* d_out, int out_size, void* d_ws, size_t ws_size,
                              hipStream_t stream) {
  const float* node_emb = (const float*)d_in[0];
  const float* w1    = (const float*)d_in[1];
  const float* root1 = (const float*)d_in[2];
  const float* bias1 = (const float*)d_in[3];
  const float* w2    = (const float*)d_in[4];
  const float* root2 = (const float*)d_in[5];
  const float* bias2 = (const float*)d_in[6];
  const int*   ei    = (const int*)d_in[7];   // [2, E]: row0 = src, row1 = dst
  const int*   et    = (const int*)d_in[8];   // [E]

  char* ws = (char*)d_ws;
  unsigned short* x1   = (unsigned short*)(ws + X1_OFF);
  int* rowptr          = (int*)(ws + RP_OFF);
  int* degcur          = (int*)(ws + DC_OFF);
  unsigned* pked       = (unsigned*)(ws + PK_OFF);
  int* sums            = (int*)(ws + SUM_OFF);
  unsigned short* wp1  = (unsigned short*)(ws + WP1_OFF);
  unsigned short* wp2  = (unsigned short*)(ws + WP2_OFF);
  unsigned short* x0b  = (unsigned short*)(ws + X0B_OFF);

  const int* srcI = ei;
  const int* dstI = ei + E_EDGES;
  const bool use_cvt = (ws_size >= WS_NEED);   // host-side constant: identical work every call

  k_prep   <<<CVT_BLKS + ZERO_BLKS + WPK_BLKS, 256, 0, stream>>>(
              node_emb, use_cvt ? x0b : nullptr, degcur, w1, root1, wp1, w2, root2, wp2);
  k_count  <<<(E_EDGES+255)/256, 256, 0, stream>>>(dstI, et, degcur);
  k_scan1  <<<NCHUNK, 256, 0, stream>>>(degcur, rowptr, sums);
  k_scan23 <<<(M_SEG+1023)/1024, 256, 0, stream>>>(rowptr, degcur, sums);
  k_scatter<<<(E_EDGES+255)/256, 256, 0, stream>>>(srcI, dstI, et, degcur, pked);

  if (use_cvt){
    k_layer<0,1><<<N_NODES/NB, 1024, 0, stream>>>(nullptr, x0b, rowptr, pked,
                                                  wp1, bias1, nullptr, x1);
  } else {
    k_layer<1,1><<<N_NODES/NB, 1024, 0, stream>>>(node_emb, nullptr, rowptr, pked,
                                                  wp1, bias1, nullptr, x1);
  }
  k_layer<0,0><<<N_NODES/NB, 1024, 0, stream>>>(nullptr, x1, rowptr, pked,
                                                wp2, bias2, (float*)d_out, nullptr);
}